// Round 1
// baseline (20283.868 us; speedup 1.0000x reference)
//
#include <hip/hip_runtime.h>
#include <math.h>

// Problem dims (fixed by reference)
constexpr int NL = 4, D = 1024, NH = 16, DH = 64, DFF = 4096, NV = 8192;
constexpr int NB = 4, NQ = 512, NM = 512, NE = 512, KLEN = 1024; // KLEN = NM+NQ

// ---------------------------------------------------------------------------
// Embedding lookup: x[b,q,:] = emb[id] * sqrt(D) (=32)
__global__ __launch_bounds__(256) void k_embed(const float* __restrict__ emb,
                                               const int* __restrict__ ids,
                                               float* __restrict__ x) {
  int row = blockIdx.x;                 // 0..NB*NQ-1
  int id = ids[row];
  const float4* src = (const float4*)(emb + (size_t)id * D);
  float4* dst = (float4*)(x + (size_t)row * D);
  for (int i = threadIdx.x; i < D / 4; i += 256) {
    float4 t = src[i];
    t.x *= 32.f; t.y *= 32.f; t.z *= 32.f; t.w *= 32.f;
    dst[i] = t;
  }
}

// ---------------------------------------------------------------------------
// Relative positional embedding r_emb[p, d]:
//   pos = KLEN-1-p ; d<D/2 -> sin(pos*inv_freq[d]) ; else cos(pos*inv_freq[d-D/2])
__global__ __launch_bounds__(256) void k_posemb(float* __restrict__ r_emb) {
  int p = blockIdx.x;
  float pos = (float)(KLEN - 1 - p);
  for (int d = threadIdx.x; d < D; d += 256) {
    int i = (d < D / 2) ? d : d - D / 2;
    float freq = (float)pow(10000.0, -(double)(2 * i) / (double)D);
    float a = pos * freq;
    r_emb[(size_t)p * D + d] = (d < D / 2) ? sinf(a) : cosf(a);
  }
}

// ---------------------------------------------------------------------------
// mem = concat(mems[l], x) along sequence
__global__ __launch_bounds__(256) void k_concat(const float* __restrict__ mems_l,
                                                const float* __restrict__ x,
                                                float* __restrict__ mem) {
  int row = blockIdx.x;                 // b*KLEN + t
  int b = row / KLEN, t = row % KLEN;
  const float4* src = (const float4*)((t < NM)
      ? (mems_l + ((size_t)b * NM + t) * D)
      : (x + ((size_t)b * NQ + (t - NM)) * D));
  float4* dst = (float4*)(mem + (size_t)row * D);
  for (int i = threadIdx.x; i < D / 4; i += 256) dst[i] = src[i];
}

// ---------------------------------------------------------------------------
// fp32 SGEMM: C[M,N] = A[M,K] @ B[K,N].  128x128 tile, BK=16, 256 thr, 8x8 micro.
// All M % 128 == 0, N % 128 == 0, K % 16 == 0 in this problem -> no bounds checks.
__global__ __launch_bounds__(256) void k_gemm(const float* __restrict__ A,
                                              const float* __restrict__ Bm,
                                              float* __restrict__ C,
                                              int Md, int Nd, int Kd) {
  __shared__ float As[16][132];   // [k][m], +4 pad breaks store conflicts
  __shared__ float Bs[16][128];   // [k][n]
  int tid = threadIdx.x;
  int tx = tid & 15, ty = tid >> 4;
  int m0 = blockIdx.y * 128, n0 = blockIdx.x * 128;
  float acc[8][8] = {{0.f}};
  for (int k0 = 0; k0 < Kd; k0 += 16) {
#pragma unroll
    for (int ld = 0; ld < 2; ++ld) {
      int idx = tid + ld * 256;
      // A tile: 128 rows x 16 k = 512 float4 loads (coalesced on k)
      int row = idx >> 2, kq = idx & 3;
      float4 t = *(const float4*)(A + (size_t)(m0 + row) * Kd + k0 + kq * 4);
      As[kq * 4 + 0][row] = t.x;
      As[kq * 4 + 1][row] = t.y;
      As[kq * 4 + 2][row] = t.z;
      As[kq * 4 + 3][row] = t.w;
      // B tile: 16 k x 128 n = 512 float4 loads (coalesced on n)
      int kk2 = idx >> 5, nq = idx & 31;
      *(float4*)&Bs[kk2][nq * 4] = *(const float4*)(Bm + (size_t)(k0 + kk2) * Nd + n0 + nq * 4);
    }
    __syncthreads();
#pragma unroll
    for (int kkk = 0; kkk < 16; ++kkk) {
      float a[8], bq[8];
      *(float4*)&a[0] = *(const float4*)&As[kkk][ty * 8];
      *(float4*)&a[4] = *(const float4*)&As[kkk][ty * 8 + 4];
      *(float4*)&bq[0] = *(const float4*)&Bs[kkk][tx * 8];
      *(float4*)&bq[4] = *(const float4*)&Bs[kkk][tx * 8 + 4];
#pragma unroll
      for (int i = 0; i < 8; ++i)
#pragma unroll
        for (int j = 0; j < 8; ++j)
          acc[i][j] = fmaf(a[i], bq[j], acc[i][j]);
    }
    __syncthreads();
  }
#pragma unroll
  for (int i = 0; i < 8; ++i) {
    float* cr = C + (size_t)(m0 + ty * 8 + i) * Nd + n0 + tx * 8;
    float4 o1 = {acc[i][0], acc[i][1], acc[i][2], acc[i][3]};
    float4 o2 = {acc[i][4], acc[i][5], acc[i][6], acc[i][7]};
    *(float4*)cr = o1;
    *(float4*)(cr + 4) = o2;
  }
}

// ---------------------------------------------------------------------------
// Attention: one block per (b, h, query-row). Scores live in LDS.
// REL=true (self-attn): score_c = ((q+u)·k_c + (q+v)·r_{c+Q-1-row}) * 0.125,
//   masked where c > NM + row (this masking exactly covers rel_shift's wraps).
// REL=false (cross-attn): score_c = (q·k_c) * 0.125, no mask, no u/v.
template <int KL, bool REL>
__global__ __launch_bounds__(256) void k_attn(const float* __restrict__ q,
                                              const float* __restrict__ kmat,
                                              const float* __restrict__ vmat,
                                              const float* __restrict__ rmat,
                                              const float* __restrict__ ubias,
                                              const float* __restrict__ vbias,
                                              float* __restrict__ av) {
  constexpr int CPT = KL / 256;
  int blk = blockIdx.x;
  int row = blk % NQ;
  int bh = blk / NQ;
  int h = bh % NH, b = bh / NH;
  __shared__ float sc[KL];
  __shared__ float qu[DH];
  __shared__ float qv[DH];
  __shared__ float red[256];
  __shared__ float pv[4][DH];
  int tid = threadIdx.x;
  if (tid < DH) {
    float qd = q[((size_t)(b * NQ + row)) * D + h * DH + tid];
    qu[tid] = REL ? (qd + ubias[h * DH + tid]) : qd;
    if (REL) qv[tid] = qd + vbias[h * DH + tid];
  }
  __syncthreads();
  float lmax = -1e30f;
  for (int cc = 0; cc < CPT; ++cc) {
    int c = cc * 256 + tid;
    float s = -1e30f;
    if (!REL || c <= NM + row) {
      const float* kp = kmat + ((size_t)b * KL + c) * D + h * DH;
      float ac = 0.f;
#pragma unroll
      for (int d = 0; d < DH; d += 4) {
        float4 k4 = *(const float4*)(kp + d);
        ac = fmaf(qu[d], k4.x, ac);
        ac = fmaf(qu[d + 1], k4.y, ac);
        ac = fmaf(qu[d + 2], k4.z, ac);
        ac = fmaf(qu[d + 3], k4.w, ac);
      }
      if (REL) {
        int dpos = c + (NQ - 1) - row;   // in [0, KLEN) for all unmasked c
        const float* rp = rmat + (size_t)dpos * D + h * DH;
        float bd = 0.f;
#pragma unroll
        for (int d = 0; d < DH; d += 4) {
          float4 r4 = *(const float4*)(rp + d);
          bd = fmaf(qv[d], r4.x, bd);
          bd = fmaf(qv[d + 1], r4.y, bd);
          bd = fmaf(qv[d + 2], r4.z, bd);
          bd = fmaf(qv[d + 3], r4.w, bd);
        }
        s = (ac + bd) * 0.125f;
      } else {
        s = ac * 0.125f;
      }
    }
    sc[c] = s;
    lmax = fmaxf(lmax, s);
  }
  red[tid] = lmax;
  __syncthreads();
  for (int off = 128; off > 0; off >>= 1) {
    if (tid < off) red[tid] = fmaxf(red[tid], red[tid + off]);
    __syncthreads();
  }
  float gmax = red[0];
  __syncthreads();
  float lsum = 0.f;
  for (int cc = 0; cc < CPT; ++cc) {
    int c = cc * 256 + tid;
    float e = __expf(sc[c] - gmax);   // masked -1e30 -> exp -> 0
    sc[c] = e;
    lsum += e;
  }
  red[tid] = lsum;
  __syncthreads();
  for (int off = 128; off > 0; off >>= 1) {
    if (tid < off) red[tid] += red[tid + off];
    __syncthreads();
  }
  float inv = 1.f / red[0];
  // p @ V: lane = head-dim (coalesced), 4 segments reduced in LDS
  int d = tid & 63, seg = tid >> 6;
  float part = 0.f;
  for (int c = seg * (KL / 4); c < (seg + 1) * (KL / 4); ++c)
    part = fmaf(sc[c], vmat[((size_t)b * KL + c) * D + h * DH + d], part);
  pv[seg][d] = part;
  __syncthreads();
  if (tid < DH) {
    av[((size_t)(b * NQ + row)) * D + h * DH + tid] =
        (pv[0][tid] + pv[1][tid] + pv[2][tid] + pv[3][tid]) * inv;
  }
}

// ---------------------------------------------------------------------------
// x = LayerNorm(x + y + bias) * g + b   (in place on x; one block per row)
__global__ __launch_bounds__(256) void k_ln(float* __restrict__ x,
                                            const float* __restrict__ y,
                                            const float* __restrict__ bias,
                                            const float* __restrict__ g,
                                            const float* __restrict__ bb) {
  int row = blockIdx.x;
  int tid = threadIdx.x;
  __shared__ float red[256];
  size_t base = (size_t)row * D + tid * 4;
  float4 xv = *(const float4*)(x + base);
  float4 yv = *(const float4*)(y + base);
  float4 bv = *(const float4*)(bias + tid * 4);
  float v0 = xv.x + yv.x + bv.x;
  float v1 = xv.y + yv.y + bv.y;
  float v2 = xv.z + yv.z + bv.z;
  float v3 = xv.w + yv.w + bv.w;
  red[tid] = v0 + v1 + v2 + v3;
  __syncthreads();
  for (int off = 128; off > 0; off >>= 1) {
    if (tid < off) red[tid] += red[tid + off];
    __syncthreads();
  }
  float mu = red[0] * (1.f / D);
  __syncthreads();
  v0 -= mu; v1 -= mu; v2 -= mu; v3 -= mu;
  red[tid] = v0 * v0 + v1 * v1 + v2 * v2 + v3 * v3;
  __syncthreads();
  for (int off = 128; off > 0; off >>= 1) {
    if (tid < off) red[tid] += red[tid + off];
    __syncthreads();
  }
  float inv = rsqrtf(red[0] * (1.f / D) + 1e-5f);
  float4 gv = *(const float4*)(g + tid * 4);
  float4 bbv = *(const float4*)(bb + tid * 4);
  float4 o;
  o.x = v0 * inv * gv.x + bbv.x;
  o.y = v1 * inv * gv.y + bbv.y;
  o.z = v2 * inv * gv.z + bbv.z;
  o.w = v3 * inv * gv.w + bbv.w;
  *(float4*)(x + base) = o;
}

// ---------------------------------------------------------------------------
// h = gelu(h + b1), exact erf variant
__global__ __launch_bounds__(256) void k_bias_gelu(float* __restrict__ h,
                                                   const float* __restrict__ b1) {
  size_t idx = ((size_t)blockIdx.x * 256 + threadIdx.x) * 4;
  int col = (int)(idx % DFF);
  float4 t = *(float4*)(h + idx);
  float4 bv = *(const float4*)(b1 + col);
  float a0 = t.x + bv.x, a1 = t.y + bv.y, a2 = t.z + bv.z, a3 = t.w + bv.w;
  const float inv_sqrt2 = 0.70710678118654752f;
  t.x = 0.5f * a0 * (1.f + erff(a0 * inv_sqrt2));
  t.y = 0.5f * a1 * (1.f + erff(a1 * inv_sqrt2));
  t.z = 0.5f * a2 * (1.f + erff(a2 * inv_sqrt2));
  t.w = 0.5f * a3 * (1.f + erff(a3 * inv_sqrt2));
  *(float4*)(h + idx) = t;
}

// ---------------------------------------------------------------------------
extern "C" void kernel_launch(void* const* d_in, const int* in_sizes, int n_in,
                              void* d_out, int out_size, void* d_ws, size_t ws_size,
                              hipStream_t stream) {
  const float* enc    = (const float*)d_in[0];
  const float* mems   = (const float*)d_in[1];
  const float* emb    = (const float*)d_in[2];
  const float* u_b    = (const float*)d_in[3];
  const float* v_b    = (const float*)d_in[4];
  const float* sa_Wq  = (const float*)d_in[5];
  const float* sa_Wk  = (const float*)d_in[6];
  const float* sa_Wv  = (const float*)d_in[7];
  const float* sa_Wr  = (const float*)d_in[8];
  const float* sa_fcW = (const float*)d_in[9];
  const float* sa_fcB = (const float*)d_in[10];
  const float* ln1_g  = (const float*)d_in[11];
  const float* ln1_b  = (const float*)d_in[12];
  const float* ca_Wq  = (const float*)d_in[13];
  const float* ca_Wk  = (const float*)d_in[14];
  const float* ca_Wv  = (const float*)d_in[15];
  const float* ca_fcW = (const float*)d_in[16];
  const float* ca_fcB = (const float*)d_in[17];
  const float* ln2_g  = (const float*)d_in[18];
  const float* ln2_b  = (const float*)d_in[19];
  const float* ff_W1  = (const float*)d_in[20];
  const float* ff_b1  = (const float*)d_in[21];
  const float* ff_W2  = (const float*)d_in[22];
  const float* ff_b2  = (const float*)d_in[23];
  const float* ln3_g  = (const float*)d_in[24];
  const float* ln3_b  = (const float*)d_in[25];
  const float* out_W  = (const float*)d_in[26];
  const int*   ids    = (const int*)d_in[27];
  float* out = (float*)d_out;

  // Workspace layout (floats). Total = 22M floats = 88 MB.
  float* ws    = (float*)d_ws;
  float* r_emb = ws;                                  // KLEN*D      = 1M
  float* xb    = r_emb + (size_t)KLEN * D;            // NB*NQ*D     = 2M
  float* yb    = xb   + (size_t)NB * NQ * D;          // 2M
  float* avb   = yb   + (size_t)NB * NQ * D;          // 2M
  float* qb    = avb  + (size_t)NB * NQ * D;          // 2M
  float* memb  = qb   + (size_t)NB * NQ * D;          // NB*KLEN*D   = 4M
  float* kb    = memb + (size_t)NB * KLEN * D;        // 4M
  float* vb    = kb   + (size_t)NB * KLEN * D;        // 4M
  float* rb    = vb   + (size_t)NB * KLEN * D;        // KLEN*D      = 1M
  float* hff   = memb;  // FF hidden (8M floats) aliases memb+kb, dead during FF

  auto gemm = [&](const float* A, const float* Bp, float* C, int Md, int Nd, int Kd) {
    dim3 g(Nd / 128, Md / 128);
    k_gemm<<<g, 256, 0, stream>>>(A, Bp, C, Md, Nd, Kd);
  };

  k_embed<<<NB * NQ, 256, 0, stream>>>(emb, ids, xb);
  k_posemb<<<KLEN, 256, 0, stream>>>(r_emb);

  for (int l = 0; l < NL; ++l) {
    size_t wo = (size_t)l * D * D;
    // ---- self attention (TransformerXL relative) ----
    k_concat<<<NB * KLEN, 256, 0, stream>>>(mems + (size_t)l * NB * NM * D, xb, memb);
    gemm(xb,    sa_Wq + wo, qb, NB * NQ,  D, D);
    gemm(memb,  sa_Wk + wo, kb, NB * KLEN, D, D);
    gemm(memb,  sa_Wv + wo, vb, NB * KLEN, D, D);
    gemm(r_emb, sa_Wr + wo, rb, KLEN, D, D);
    k_attn<KLEN, true><<<NB * NH * NQ, 256, 0, stream>>>(qb, kb, vb, rb, u_b, v_b, avb);
    gemm(avb, sa_fcW + wo, yb, NB * NQ, D, D);
    k_ln<<<NB * NQ, 256, 0, stream>>>(xb, yb, sa_fcB + (size_t)l * D,
                                      ln1_g + (size_t)l * D, ln1_b + (size_t)l * D);
    // ---- cross attention ----
    gemm(xb,  ca_Wq + wo, qb, NB * NQ, D, D);
    gemm(enc, ca_Wk + wo, kb, NB * NE, D, D);
    gemm(enc, ca_Wv + wo, vb, NB * NE, D, D);
    k_attn<NE, false><<<NB * NH * NQ, 256, 0, stream>>>(qb, kb, vb, nullptr, nullptr, nullptr, avb);
    gemm(avb, ca_fcW + wo, yb, NB * NQ, D, D);
    k_ln<<<NB * NQ, 256, 0, stream>>>(xb, yb, ca_fcB + (size_t)l * D,
                                      ln2_g + (size_t)l * D, ln2_b + (size_t)l * D);
    // ---- feed forward ----
    gemm(xb, ff_W1 + (size_t)l * D * DFF, hff, NB * NQ, DFF, D);
    k_bias_gelu<<<(NB * NQ * DFF) / 1024, 256, 0, stream>>>(hff, ff_b1 + (size_t)l * DFF);
    gemm(hff, ff_W2 + (size_t)l * DFF * D, yb, NB * NQ, D, DFF);
    k_ln<<<NB * NQ, 256, 0, stream>>>(xb, yb, ff_b2 + (size_t)l * D,
                                      ln3_g + (size_t)l * D, ln3_b + (size_t)l * D);
  }
  // ---- output projection ----
  gemm(xb, out_W, out, NB * NQ, NV, D);
}

// Round 2
// 12804.732 us; speedup vs baseline: 1.5841x; 1.5841x over previous
//
#include <hip/hip_runtime.h>
#include <math.h>

// Problem dims (fixed by reference)
constexpr int NL = 4, D = 1024, NH = 16, DH = 64, DFF = 4096, NV = 8192;
constexpr int NB = 4, NQ = 512, NM = 512, NE = 512, KLEN = 1024; // KLEN = NM+NQ

// ---------------------------------------------------------------------------
// Embedding lookup: x[b,q,:] = emb[id] * sqrt(D) (=32)
__global__ __launch_bounds__(256) void k_embed(const float* __restrict__ emb,
                                               const int* __restrict__ ids,
                                               float* __restrict__ x) {
  int row = blockIdx.x;                 // 0..NB*NQ-1
  int id = ids[row];
  const float4* src = (const float4*)(emb + (size_t)id * D);
  float4* dst = (float4*)(x + (size_t)row * D);
  for (int i = threadIdx.x; i < D / 4; i += 256) {
    float4 t = src[i];
    t.x *= 32.f; t.y *= 32.f; t.z *= 32.f; t.w *= 32.f;
    dst[i] = t;
  }
}

// ---------------------------------------------------------------------------
// Relative positional embedding r_emb[p, d]
__global__ __launch_bounds__(256) void k_posemb(float* __restrict__ r_emb) {
  int p = blockIdx.x;
  float pos = (float)(KLEN - 1 - p);
  for (int d = threadIdx.x; d < D; d += 256) {
    int i = (d < D / 2) ? d : d - D / 2;
    float freq = (float)pow(10000.0, -(double)(2 * i) / (double)D);
    float a = pos * freq;
    r_emb[(size_t)p * D + d] = (d < D / 2) ? sinf(a) : cosf(a);
  }
}

// ---------------------------------------------------------------------------
// mem = concat(mems[l], x) along sequence
__global__ __launch_bounds__(256) void k_concat(const float* __restrict__ mems_l,
                                                const float* __restrict__ x,
                                                float* __restrict__ mem) {
  int row = blockIdx.x;                 // b*KLEN + t
  int b = row / KLEN, t = row % KLEN;
  const float4* src = (const float4*)((t < NM)
      ? (mems_l + ((size_t)b * NM + t) * D)
      : (x + ((size_t)b * NQ + (t - NM)) * D));
  float4* dst = (float4*)(mem + (size_t)row * D);
  for (int i = threadIdx.x; i < D / 4; i += 256) dst[i] = src[i];
}

// ---------------------------------------------------------------------------
// fp32 SGEMM: C[M,N] = A[M,K] @ B[K,N].  128x128 tile, BK=16, 256 thr, 8x8 micro.
__global__ __launch_bounds__(256) void k_gemm(const float* __restrict__ A,
                                              const float* __restrict__ Bm,
                                              float* __restrict__ C,
                                              int Md, int Nd, int Kd) {
  __shared__ float As[16][132];   // [k][m]
  __shared__ float Bs[16][128];   // [k][n]
  int tid = threadIdx.x;
  int tx = tid & 15, ty = tid >> 4;
  int m0 = blockIdx.y * 128, n0 = blockIdx.x * 128;
  float acc[8][8] = {{0.f}};
  for (int k0 = 0; k0 < Kd; k0 += 16) {
#pragma unroll
    for (int ld = 0; ld < 2; ++ld) {
      int idx = tid + ld * 256;
      int row = idx >> 2, kq = idx & 3;
      float4 t = *(const float4*)(A + (size_t)(m0 + row) * Kd + k0 + kq * 4);
      As[kq * 4 + 0][row] = t.x;
      As[kq * 4 + 1][row] = t.y;
      As[kq * 4 + 2][row] = t.z;
      As[kq * 4 + 3][row] = t.w;
      int kk2 = idx >> 5, nq = idx & 31;
      *(float4*)&Bs[kk2][nq * 4] = *(const float4*)(Bm + (size_t)(k0 + kk2) * Nd + n0 + nq * 4);
    }
    __syncthreads();
#pragma unroll
    for (int kkk = 0; kkk < 16; ++kkk) {
      float a[8], bq[8];
      *(float4*)&a[0] = *(const float4*)&As[kkk][ty * 8];
      *(float4*)&a[4] = *(const float4*)&As[kkk][ty * 8 + 4];
      *(float4*)&bq[0] = *(const float4*)&Bs[kkk][tx * 8];
      *(float4*)&bq[4] = *(const float4*)&Bs[kkk][tx * 8 + 4];
#pragma unroll
      for (int i = 0; i < 8; ++i)
#pragma unroll
        for (int j = 0; j < 8; ++j)
          acc[i][j] = fmaf(a[i], bq[j], acc[i][j]);
    }
    __syncthreads();
  }
#pragma unroll
  for (int i = 0; i < 8; ++i) {
    float* cr = C + (size_t)(m0 + ty * 8 + i) * Nd + n0 + tx * 8;
    float4 o1 = {acc[i][0], acc[i][1], acc[i][2], acc[i][3]};
    float4 o2 = {acc[i][4], acc[i][5], acc[i][6], acc[i][7]};
    *(float4*)cr = o1;
    *(float4*)(cr + 4) = o2;
  }
}

// ---------------------------------------------------------------------------
// Score NT-GEMM over one (b): C[h][i][j] = sum_d (A[i][d]+bias[h][d]) * B[j][d]
// A rows strided D (head slice h*DH), B rows strided D. K = DH = 64.
// SHIFT=false: plain write to C[h][i][j].
// SHIFT=true (TXL BD term): scatter-accumulate C[h][i][p-(Q-1)+i] += val for
//   p >= (Q-1)-i. This exactly covers the unmasked region of rel_shift.
template <bool SHIFT>
__global__ __launch_bounds__(256) void k_qkt(const float* __restrict__ A,
                                             const float* __restrict__ Bm,
                                             const float* __restrict__ bias,
                                             float* __restrict__ C,
                                             int cols) {
  __shared__ float As[16][132];
  __shared__ float Bs[16][132];
  int h = blockIdx.z;
  int m0 = blockIdx.y * 128, n0 = blockIdx.x * 128;
  const float* Ab = A + h * DH;
  const float* Bb = Bm + h * DH;
  float* Cb = C + (size_t)h * NQ * cols;
  int tid = threadIdx.x, tx = tid & 15, ty = tid >> 4;
  float acc[8][8] = {{0.f}};
  for (int k0 = 0; k0 < DH; k0 += 16) {
#pragma unroll
    for (int ld = 0; ld < 2; ++ld) {
      int idx = tid + ld * 256;
      int row = idx >> 2, kq = idx & 3;
      float4 t = *(const float4*)(Ab + (size_t)(m0 + row) * D + k0 + kq * 4);
      float4 bv = {0.f, 0.f, 0.f, 0.f};
      if (bias) bv = *(const float4*)(bias + h * DH + k0 + kq * 4);
      As[kq * 4 + 0][row] = t.x + bv.x;
      As[kq * 4 + 1][row] = t.y + bv.y;
      As[kq * 4 + 2][row] = t.z + bv.z;
      As[kq * 4 + 3][row] = t.w + bv.w;
      float4 tb = *(const float4*)(Bb + (size_t)(n0 + row) * D + k0 + kq * 4);
      Bs[kq * 4 + 0][row] = tb.x;
      Bs[kq * 4 + 1][row] = tb.y;
      Bs[kq * 4 + 2][row] = tb.z;
      Bs[kq * 4 + 3][row] = tb.w;
    }
    __syncthreads();
#pragma unroll
    for (int kkk = 0; kkk < 16; ++kkk) {
      float a[8], bq[8];
      *(float4*)&a[0] = *(const float4*)&As[kkk][ty * 8];
      *(float4*)&a[4] = *(const float4*)&As[kkk][ty * 8 + 4];
      *(float4*)&bq[0] = *(const float4*)&Bs[kkk][tx * 8];
      *(float4*)&bq[4] = *(const float4*)&Bs[kkk][tx * 8 + 4];
#pragma unroll
      for (int i = 0; i < 8; ++i)
#pragma unroll
        for (int j = 0; j < 8; ++j)
          acc[i][j] = fmaf(a[i], bq[j], acc[i][j]);
    }
    __syncthreads();
  }
  if (!SHIFT) {
#pragma unroll
    for (int i = 0; i < 8; ++i) {
      float* cr = Cb + (size_t)(m0 + ty * 8 + i) * cols + n0 + tx * 8;
      float4 o1 = {acc[i][0], acc[i][1], acc[i][2], acc[i][3]};
      float4 o2 = {acc[i][4], acc[i][5], acc[i][6], acc[i][7]};
      *(float4*)cr = o1;
      *(float4*)(cr + 4) = o2;
    }
  } else {
#pragma unroll
    for (int i = 0; i < 8; ++i) {
      int ig = m0 + ty * 8 + i;
      float* cr = Cb + (size_t)ig * cols;
#pragma unroll
      for (int j = 0; j < 8; ++j) {
        int p = n0 + tx * 8 + j;
        int jj = p - (NQ - 1) + ig;
        if (jj >= 0) cr[jj] += acc[i][j];
      }
    }
  }
}

// ---------------------------------------------------------------------------
// Row softmax over sc[h][i][0..KL): scale 0.125, (MASK) j>NM+i -> -inf
template <int KL, bool MASK>
__global__ __launch_bounds__(256) void k_softmax(float* __restrict__ sc) {
  int i = blockIdx.x, h = blockIdx.y, tid = threadIdx.x;
  float* r = sc + ((size_t)h * NQ + i) * KL;
  __shared__ float red[256];
  constexpr int NV4 = KL / 4;
  float4 v = {-1e30f, -1e30f, -1e30f, -1e30f};
  if (tid < NV4) {
    v = ((float4*)r)[tid];
    v.x *= 0.125f; v.y *= 0.125f; v.z *= 0.125f; v.w *= 0.125f;
    if (MASK) {
      int j = tid * 4;
      if (j + 0 > NM + i) v.x = -1e30f;
      if (j + 1 > NM + i) v.y = -1e30f;
      if (j + 2 > NM + i) v.z = -1e30f;
      if (j + 3 > NM + i) v.w = -1e30f;
    }
  }
  red[tid] = fmaxf(fmaxf(v.x, v.y), fmaxf(v.z, v.w));
  __syncthreads();
  for (int off = 128; off > 0; off >>= 1) {
    if (tid < off) red[tid] = fmaxf(red[tid], red[tid + off]);
    __syncthreads();
  }
  float gm = red[0];
  __syncthreads();
  float4 e = {0.f, 0.f, 0.f, 0.f};
  if (tid < NV4) {
    e.x = __expf(v.x - gm);
    e.y = __expf(v.y - gm);
    e.z = __expf(v.z - gm);
    e.w = __expf(v.w - gm);
  }
  red[tid] = e.x + e.y + e.z + e.w;
  __syncthreads();
  for (int off = 128; off > 0; off >>= 1) {
    if (tid < off) red[tid] += red[tid + off];
    __syncthreads();
  }
  float inv = 1.f / red[0];
  if (tid < NV4) {
    e.x *= inv; e.y *= inv; e.z *= inv; e.w *= inv;
    ((float4*)r)[tid] = e;
  }
}

// ---------------------------------------------------------------------------
// PV NN-GEMM per (b): av[i][h*DH+d] = sum_j P[h][i][j] * V[j][h*DH+d]
// Tile 128(M) x 64(N=DH), BK=16, 256 thr, micro 8x4.
template <int KL>
__global__ __launch_bounds__(256) void k_pv(const float* __restrict__ sc,
                                            const float* __restrict__ V,
                                            float* __restrict__ av) {
  __shared__ float As[16][132];
  __shared__ float Bs[16][68];
  int h = blockIdx.y;
  int m0 = blockIdx.x * 128;
  const float* P = sc + (size_t)h * NQ * KL;
  const float* Vb = V + h * DH;
  int tid = threadIdx.x, tx = tid & 15, ty = tid >> 4;
  float acc[8][4] = {{0.f}};
  for (int k0 = 0; k0 < KL; k0 += 16) {
#pragma unroll
    for (int ld = 0; ld < 2; ++ld) {
      int idx = tid + ld * 256;
      int row = idx >> 2, kq = idx & 3;
      float4 t = *(const float4*)(P + (size_t)(m0 + row) * KL + k0 + kq * 4);
      As[kq * 4 + 0][row] = t.x;
      As[kq * 4 + 1][row] = t.y;
      As[kq * 4 + 2][row] = t.z;
      As[kq * 4 + 3][row] = t.w;
    }
    {
      int kk = tid >> 4, nq = tid & 15;
      *(float4*)&Bs[kk][nq * 4] = *(const float4*)(Vb + (size_t)(k0 + kk) * D + nq * 4);
    }
    __syncthreads();
#pragma unroll
    for (int kkk = 0; kkk < 16; ++kkk) {
      float a[8], bq[4];
      *(float4*)&a[0] = *(const float4*)&As[kkk][ty * 8];
      *(float4*)&a[4] = *(const float4*)&As[kkk][ty * 8 + 4];
      *(float4*)&bq[0] = *(const float4*)&Bs[kkk][tx * 4];
#pragma unroll
      for (int i = 0; i < 8; ++i)
#pragma unroll
        for (int j = 0; j < 4; ++j)
          acc[i][j] = fmaf(a[i], bq[j], acc[i][j]);
    }
    __syncthreads();
  }
#pragma unroll
  for (int i = 0; i < 8; ++i) {
    float4 o = {acc[i][0], acc[i][1], acc[i][2], acc[i][3]};
    *(float4*)(av + (size_t)(m0 + ty * 8 + i) * D + h * DH + tx * 4) = o;
  }
}

// ---------------------------------------------------------------------------
// x = LayerNorm(x + y + bias) * g + b   (in place on x; one block per row)
__global__ __launch_bounds__(256) void k_ln(float* __restrict__ x,
                                            const float* __restrict__ y,
                                            const float* __restrict__ bias,
                                            const float* __restrict__ g,
                                            const float* __restrict__ bb) {
  int row = blockIdx.x;
  int tid = threadIdx.x;
  __shared__ float red[256];
  size_t base = (size_t)row * D + tid * 4;
  float4 xv = *(const float4*)(x + base);
  float4 yv = *(const float4*)(y + base);
  float4 bv = *(const float4*)(bias + tid * 4);
  float v0 = xv.x + yv.x + bv.x;
  float v1 = xv.y + yv.y + bv.y;
  float v2 = xv.z + yv.z + bv.z;
  float v3 = xv.w + yv.w + bv.w;
  red[tid] = v0 + v1 + v2 + v3;
  __syncthreads();
  for (int off = 128; off > 0; off >>= 1) {
    if (tid < off) red[tid] += red[tid + off];
    __syncthreads();
  }
  float mu = red[0] * (1.f / D);
  __syncthreads();
  v0 -= mu; v1 -= mu; v2 -= mu; v3 -= mu;
  red[tid] = v0 * v0 + v1 * v1 + v2 * v2 + v3 * v3;
  __syncthreads();
  for (int off = 128; off > 0; off >>= 1) {
    if (tid < off) red[tid] += red[tid + off];
    __syncthreads();
  }
  float inv = rsqrtf(red[0] * (1.f / D) + 1e-5f);
  float4 gv = *(const float4*)(g + tid * 4);
  float4 bbv = *(const float4*)(bb + tid * 4);
  float4 o;
  o.x = v0 * inv * gv.x + bbv.x;
  o.y = v1 * inv * gv.y + bbv.y;
  o.z = v2 * inv * gv.z + bbv.z;
  o.w = v3 * inv * gv.w + bbv.w;
  *(float4*)(x + base) = o;
}

// ---------------------------------------------------------------------------
// h = gelu(h + b1), exact erf variant
__global__ __launch_bounds__(256) void k_bias_gelu(float* __restrict__ h,
                                                   const float* __restrict__ b1) {
  size_t idx = ((size_t)blockIdx.x * 256 + threadIdx.x) * 4;
  int col = (int)(idx % DFF);
  float4 t = *(float4*)(h + idx);
  float4 bv = *(const float4*)(b1 + col);
  float a0 = t.x + bv.x, a1 = t.y + bv.y, a2 = t.z + bv.z, a3 = t.w + bv.w;
  const float inv_sqrt2 = 0.70710678118654752f;
  t.x = 0.5f * a0 * (1.f + erff(a0 * inv_sqrt2));
  t.y = 0.5f * a1 * (1.f + erff(a1 * inv_sqrt2));
  t.z = 0.5f * a2 * (1.f + erff(a2 * inv_sqrt2));
  t.w = 0.5f * a3 * (1.f + erff(a3 * inv_sqrt2));
  *(float4*)(h + idx) = t;
}

// ---------------------------------------------------------------------------
extern "C" void kernel_launch(void* const* d_in, const int* in_sizes, int n_in,
                              void* d_out, int out_size, void* d_ws, size_t ws_size,
                              hipStream_t stream) {
  const float* enc    = (const float*)d_in[0];
  const float* mems   = (const float*)d_in[1];
  const float* emb    = (const float*)d_in[2];
  const float* u_b    = (const float*)d_in[3];
  const float* v_b    = (const float*)d_in[4];
  const float* sa_Wq  = (const float*)d_in[5];
  const float* sa_Wk  = (const float*)d_in[6];
  const float* sa_Wv  = (const float*)d_in[7];
  const float* sa_Wr  = (const float*)d_in[8];
  const float* sa_fcW = (const float*)d_in[9];
  const float* sa_fcB = (const float*)d_in[10];
  const float* ln1_g  = (const float*)d_in[11];
  const float* ln1_b  = (const float*)d_in[12];
  const float* ca_Wq  = (const float*)d_in[13];
  const float* ca_Wk  = (const float*)d_in[14];
  const float* ca_Wv  = (const float*)d_in[15];
  const float* ca_fcW = (const float*)d_in[16];
  const float* ca_fcB = (const float*)d_in[17];
  const float* ln2_g  = (const float*)d_in[18];
  const float* ln2_b  = (const float*)d_in[19];
  const float* ff_W1  = (const float*)d_in[20];
  const float* ff_b1  = (const float*)d_in[21];
  const float* ff_W2  = (const float*)d_in[22];
  const float* ff_b2  = (const float*)d_in[23];
  const float* ln3_g  = (const float*)d_in[24];
  const float* ln3_b  = (const float*)d_in[25];
  const float* out_W  = (const float*)d_in[26];
  const int*   ids    = (const int*)d_in[27];
  float* out = (float*)d_out;

  // Workspace layout (floats). Total = 30M floats = 120 MB.
  float* ws    = (float*)d_ws;
  float* r_emb = ws;                                  // KLEN*D      = 1M
  float* xb    = r_emb + (size_t)KLEN * D;            // NB*NQ*D     = 2M
  float* yb    = xb   + (size_t)NB * NQ * D;          // 2M
  float* avb   = yb   + (size_t)NB * NQ * D;          // 2M
  float* qb    = avb  + (size_t)NB * NQ * D;          // 2M
  float* memb  = qb   + (size_t)NB * NQ * D;          // NB*KLEN*D   = 4M
  float* kb    = memb + (size_t)NB * KLEN * D;        // 4M
  float* vb    = kb   + (size_t)NB * KLEN * D;        // 4M
  float* rb    = vb   + (size_t)NB * KLEN * D;        // KLEN*D      = 1M
  float* scb   = rb   + (size_t)KLEN * D;             // NH*NQ*KLEN  = 8M (per-b scores)
  float* hff   = memb;  // FF hidden (8M floats) aliases memb+kb, dead during FF

  auto gemm = [&](const float* A, const float* Bp, float* C, int Md, int Nd, int Kd) {
    dim3 g(Nd / 128, Md / 128);
    k_gemm<<<g, 256, 0, stream>>>(A, Bp, C, Md, Nd, Kd);
  };

  k_embed<<<NB * NQ, 256, 0, stream>>>(emb, ids, xb);
  k_posemb<<<KLEN, 256, 0, stream>>>(r_emb);

  for (int l = 0; l < NL; ++l) {
    size_t wo = (size_t)l * D * D;
    // ---- self attention (TransformerXL relative) ----
    k_concat<<<NB * KLEN, 256, 0, stream>>>(mems + (size_t)l * NB * NM * D, xb, memb);
    gemm(xb,    sa_Wq + wo, qb, NB * NQ,  D, D);
    gemm(memb,  sa_Wk + wo, kb, NB * KLEN, D, D);
    gemm(memb,  sa_Wv + wo, vb, NB * KLEN, D, D);
    gemm(r_emb, sa_Wr + wo, rb, KLEN, D, D);
    for (int b = 0; b < NB; ++b) {
      const float* qB = qb + (size_t)b * NQ * D;
      dim3 gs(KLEN / 128, NQ / 128, NH);
      k_qkt<false><<<gs, 256, 0, stream>>>(qB, kb + (size_t)b * KLEN * D, u_b, scb, KLEN);
      k_qkt<true><<<gs, 256, 0, stream>>>(qB, rb, v_b, scb, KLEN);
      k_softmax<KLEN, true><<<dim3(NQ, NH), 256, 0, stream>>>(scb);
      k_pv<KLEN><<<dim3(NQ / 128, NH), 256, 0, stream>>>(scb, vb + (size_t)b * KLEN * D,
                                                         avb + (size_t)b * NQ * D);
    }
    gemm(avb, sa_fcW + wo, yb, NB * NQ, D, D);
    k_ln<<<NB * NQ, 256, 0, stream>>>(xb, yb, sa_fcB + (size_t)l * D,
                                      ln1_g + (size_t)l * D, ln1_b + (size_t)l * D);
    // ---- cross attention ----
    gemm(xb,  ca_Wq + wo, qb, NB * NQ, D, D);
    gemm(enc, ca_Wk + wo, kb, NB * NE, D, D);
    gemm(enc, ca_Wv + wo, vb, NB * NE, D, D);
    for (int b = 0; b < NB; ++b) {
      const float* qB = qb + (size_t)b * NQ * D;
      dim3 gs(NE / 128, NQ / 128, NH);
      k_qkt<false><<<gs, 256, 0, stream>>>(qB, kb + (size_t)b * NE * D, nullptr, scb, NE);
      k_softmax<NE, false><<<dim3(NQ, NH), 256, 0, stream>>>(scb);
      k_pv<NE><<<dim3(NQ / 128, NH), 256, 0, stream>>>(scb, vb + (size_t)b * NE * D,
                                                       avb + (size_t)b * NQ * D);
    }
    gemm(avb, ca_fcW + wo, yb, NB * NQ, D, D);
    k_ln<<<NB * NQ, 256, 0, stream>>>(xb, yb, ca_fcB + (size_t)l * D,
                                      ln2_g + (size_t)l * D, ln2_b + (size_t)l * D);
    // ---- feed forward ----
    gemm(xb, ff_W1 + (size_t)l * D * DFF, hff, NB * NQ, DFF, D);
    k_bias_gelu<<<(NB * NQ * DFF) / 1024, 256, 0, stream>>>(hff, ff_b1 + (size_t)l * DFF);
    gemm(hff, ff_W2 + (size_t)l * DFF * D, yb, NB * NQ, D, DFF);
    k_ln<<<NB * NQ, 256, 0, stream>>>(xb, yb, ff_b2 + (size_t)l * D,
                                      ln3_g + (size_t)l * D, ln3_b + (size_t)l * D);
  }
  // ---- output projection ----
  gemm(xb, out_W, out, NB * NQ, NV, D);
}